// Round 6
// baseline (1277.937 us; speedup 1.0000x reference)
//
#include <hip/hip_runtime.h>
#include <cstdint>

#define PAD 2048
#define KG 1408   // 3*256 conv + 640 cond

typedef float f32x4 __attribute__((ext_vector_type(4)));
typedef __bf16 bf16x8 __attribute__((ext_vector_type(8)));

__device__ __forceinline__ void g2l16(const void* g, void* l) {
    __builtin_amdgcn_global_load_lds(
        (__attribute__((address_space(1))) void*)(uintptr_t)g,
        (__attribute__((address_space(3))) void*)(uint32_t)(uintptr_t)l,
        16, 0, 0);
}

// ---------------- setup kernels ----------------

__global__ void cvt_bf16_kernel(const float* __restrict__ src, __bf16* __restrict__ dst, int n) {
    int idx = blockIdx.x * 256 + threadIdx.x;
    if (idx < n) dst[idx] = (__bf16)src[idx];
}

// whole padded started buffer: pad rows = 0, data rows = audio @ w_start + b_start
__global__ void init_started_kernel(const float* __restrict__ audio, const float* __restrict__ w_start,
                                    const float* __restrict__ b_start, __bf16* __restrict__ started_pad) {
    int pr = blockIdx.x, c = threadIdx.x;
    int off = pr & 8191;
    float s = 0.f;
    if (off >= PAD && off < PAD + 4096) {
        int r = ((pr >> 13) << 12) + (off - PAD);
        float a0 = audio[r * 4 + 0], a1 = audio[r * 4 + 1], a2 = audio[r * 4 + 2], a3 = audio[r * 4 + 3];
        s = b_start[c] + a0 * w_start[c] + a1 * w_start[256 + c] + a2 * w_start[512 + c] + a3 * w_start[768 + c];
    }
    started_pad[(size_t)pr * 256 + c] = (__bf16)s;
}

// Build Wg[i][n'][k] bf16 (n' interleaved by 16: tanh16/sig16 groups), k: 0-767 conv taps, 768-1407 cond
__global__ void transpose_gate(const float* __restrict__ w_in, const float* __restrict__ w_cond,
                               __bf16* __restrict__ Wg) {
    __shared__ float tile[64][65];
    int i = blockIdx.z;
    int k0 = blockIdx.y * 64, n0 = blockIdx.x * 64;
    int tid = threadIdx.x, c = tid & 63, rr = tid >> 6;
    for (int it = 0; it < 16; ++it) {
        int kl = it * 4 + rr;
        int k = k0 + kl;
        int np = n0 + c;
        int phys = ((np >> 4) & 1) * 256 + (np >> 5) * 16 + (np & 15);
        float v;
        if (k < 768) v = w_in[((i * 3 + (k >> 8)) * 256 + (k & 255)) * 512 + phys];
        else         v = w_cond[(i * 640 + (k - 768)) * 512 + phys];
        tile[kl][c] = v;
    }
    __syncthreads();
    for (int it = 0; it < 16; ++it) {
        int nl = it * 4 + rr;
        Wg[(size_t)(i * 512 + n0 + nl) * KG + k0 + c] = (__bf16)tile[c][nl];
    }
}

// generic K x N fp32 -> [N][K] bf16 transpose (tiles of 64x64)
__global__ void transpose_kn(const float* __restrict__ src, __bf16* __restrict__ dst,
                             int K, int N, int srcLS, int dstLS) {
    __shared__ float tile[64][65];
    int i = blockIdx.z;
    int k0 = blockIdx.y * 64, n0 = blockIdx.x * 64;
    int tid = threadIdx.x, c = tid & 63, rr = tid >> 6;
    const float* s = src + (size_t)i * srcLS;
    __bf16* dp = dst + (size_t)i * dstLS;
    for (int it = 0; it < 16; ++it) {
        int kl = it * 4 + rr;
        tile[kl][c] = s[(k0 + kl) * N + n0 + c];
    }
    __syncthreads();
    for (int it = 0; it < 16; ++it) {
        int nl = it * 4 + rr;
        dp[(size_t)(n0 + nl) * K + k0 + c] = (__bf16)tile[c][nl];
    }
}

__global__ void bias_gate_kernel(const float* __restrict__ b_in, const float* __restrict__ b_cond,
                                 float* __restrict__ bias) {
    int idx = blockIdx.x * 256 + threadIdx.x;   // 0..6143
    int i = idx >> 9, np = idx & 511;
    int phys = ((np >> 4) & 1) * 256 + (np >> 5) * 16 + (np & 15);
    bias[idx] = b_in[i * 512 + phys] + b_cond[i * 512 + phys];
}

// blocks 0..95: wfold[i][k][c] = sum_j w_res_skip[i][k][j] * w_end[j][c]  (i=11 uses w_res_last)
// block 96: outconst[c] = b_end[c] + (sum_i b_res_skip[i] + b_res_last) @ w_end
__global__ void wfold_kernel(const float* __restrict__ w_res, const float* __restrict__ w_res_last,
                             const float* __restrict__ w_end, const float* __restrict__ b_res,
                             const float* __restrict__ b_res_last, const float* __restrict__ b_end,
                             float* __restrict__ wfold, float* __restrict__ outconst) {
    if (blockIdx.x == 96) {
        __shared__ float red[256][8];
        int j = threadIdx.x;
        float bsum = b_res_last[j];
        for (int i = 0; i < 11; ++i) bsum += b_res[i * 512 + 256 + j];
        for (int c = 0; c < 8; ++c) red[j][c] = bsum * w_end[j * 8 + c];
        __syncthreads();
        if (j < 8) {
            float s = b_end[j];
            for (int t = 0; t < 256; ++t) s += red[t][j];
            outconst[j] = s;
        }
        return;
    }
    int idx = blockIdx.x * 256 + threadIdx.x;   // 0..24575
    int i = idx >> 11, rem = idx & 2047, k = rem >> 3, c = rem & 7;
    float s = 0.f;
    if (i < 11) {
        const float* wr = w_res + (size_t)(i * 256 + k) * 512 + 256;
        for (int j = 0; j < 256; ++j) s += wr[j] * w_end[j * 8 + c];
    } else {
        const float* wr = w_res_last + k * 256;
        for (int j = 0; j < 256; ++j) s += wr[j] * w_end[j * 8 + c];
    }
    wfold[idx] = s;
}

// ---------------- main GEMM kernels ----------------

// fused conv + cond + gate. LDS double-buffer, one barrier per k-step; single
// prefetch reg-set (tile k+2 issued during compute of k) -> VGPR ~84.
// Grid: x = m (fast, 256), y = n (4) so the 4 A-sharing n-blocks land on one XCD.
__global__ __launch_bounds__(256) void gate_kernel(
    const __bf16* __restrict__ started_pad, const __bf16* __restrict__ spect,
    const __bf16* __restrict__ Wg,     // layer base [512][1408]
    const float* __restrict__ bias,    // layer base [512] (interleaved order)
    __bf16* __restrict__ activated, int d) {
    __shared__ __align__(16) __bf16 As[2][128 * 32];
    __shared__ __align__(16) __bf16 Bs[2][128 * 32];
    const int tid = threadIdx.x;
    const int m0 = blockIdx.x * 128;
    const int n0 = blockIdx.y * 128;
    const int padbase = ((m0 >> 12) << 13) + PAD + (m0 & 4095);
    const int srow = tid >> 2;
    const int skq = (tid & 3) * 8;
    const int wave = tid >> 6, lane = tid & 63;
    const int wm = (wave >> 1) * 64, wn = (wave & 1) * 64;
    const int quad = lane >> 4, l15 = lane & 15;

    f32x4 acc[4][4];
    for (int i = 0; i < 4; i++)
        for (int j = 0; j < 4; j++) acc[i][j] = f32x4{0.f, 0.f, 0.f, 0.f};

    const __bf16* Bbase = Wg + (n0 + srow) * KG + skq;

    bf16x8 rA0, rA1, rB0, rB1;
    auto loadTile = [&](int kk) {
        const __bf16* gA0;
        int rstride;
        if (kk < 768) {
            int tap = kk >> 8;
            int koff = kk & 255;
            gA0 = started_pad + (padbase + srow + (tap - 1) * d) * 256 + koff + skq;
            rstride = 256;
        } else {
            gA0 = spect + (m0 + srow) * 640 + (kk - 768) + skq;
            rstride = 640;
        }
        rA0 = *(const bf16x8*)gA0;
        rA1 = *(const bf16x8*)(gA0 + 64 * rstride);
        const __bf16* gB0 = Bbase + kk;
        rB0 = *(const bf16x8*)gB0;
        rB1 = *(const bf16x8*)(gB0 + 64 * KG);
    };

    // prologue: tile 0 -> buf0, tile 1 -> regs
    loadTile(0);
    *(bf16x8*)&As[0][srow * 32 + skq] = rA0;
    *(bf16x8*)&As[0][(64 + srow) * 32 + skq] = rA1;
    *(bf16x8*)&Bs[0][srow * 32 + skq] = rB0;
    *(bf16x8*)&Bs[0][(64 + srow) * 32 + skq] = rB1;
    loadTile(32);
    __syncthreads();

    for (int ks = 0; ks < 44; ++ks) {
        const int cur = ks & 1, nxt = cur ^ 1;
        bf16x8 a[4], b[4];
        for (int mi = 0; mi < 4; mi++) a[mi] = *(const bf16x8*)&As[cur][(wm + mi * 16 + l15) * 32 + quad * 8];
        for (int ni = 0; ni < 4; ni++) b[ni] = *(const bf16x8*)&Bs[cur][(wn + ni * 16 + l15) * 32 + quad * 8];
        if (ks + 1 < 44) {
            *(bf16x8*)&As[nxt][srow * 32 + skq] = rA0;
            *(bf16x8*)&As[nxt][(64 + srow) * 32 + skq] = rA1;
            *(bf16x8*)&Bs[nxt][srow * 32 + skq] = rB0;
            *(bf16x8*)&Bs[nxt][(64 + srow) * 32 + skq] = rB1;
        }
        if (ks + 2 < 44) loadTile((ks + 2) * 32);
        for (int mi = 0; mi < 4; mi++)
            for (int ni = 0; ni < 4; ni++)
                acc[mi][ni] = __builtin_amdgcn_mfma_f32_16x16x32_bf16(a[mi], b[ni], acc[mi][ni], 0, 0, 0);
        __syncthreads();
    }

    // epilogue: gating. n' pairs: (ni even = tanh group, ni odd = sigmoid of same 16 channels)
    int chbase = ((n0 + wn) >> 1) + l15;
    for (int nj = 0; nj < 2; ++nj) {
        int colT = wn + nj * 32 + l15;
        float bt = bias[n0 + colT];
        float bs = bias[n0 + colT + 16];
        int ch = chbase + nj * 16;
        for (int mi = 0; mi < 4; ++mi) {
            for (int reg = 0; reg < 4; ++reg) {
                int r = m0 + wm + mi * 16 + quad * 4 + reg;
                float xt = acc[mi][2 * nj][reg] + bt;
                float xs = acc[mi][2 * nj + 1][reg] + bs;
                float th = 2.f / (1.f + __expf(-2.f * xt)) - 1.f;
                float sg = 1.f / (1.f + __expf(-xs));
                activated[r * 256 + ch] = (__bf16)(th * sg);
            }
        }
    }
}

// rs_res = activated @ Wr + b_res ; started_pad += rs_res (bf16 RMW)
// Grid (256,2): x = m (fast) so the reader of m-tile x sits on the XCD that produced it.
// Blocks with blockIdx.y==0 also accumulate out += activated @ wfold (init on layer 0).
__global__ __launch_bounds__(256) void res_kernel(
    const __bf16* __restrict__ activated, const __bf16* __restrict__ Wr,  // [256][256]
    const float* __restrict__ b_res,      // layer base (first 256 cols used)
    const float* __restrict__ wfold,      // layer base [256][8]
    const float* __restrict__ outconst,
    __bf16* __restrict__ started_pad, float* __restrict__ out, int initOut) {
    __shared__ __align__(16) __bf16 As[128 * 32];
    __shared__ __align__(16) __bf16 Bs[128 * 32];
    __shared__ __align__(16) float Wf[2048];   // 256 x 8
    const int tid = threadIdx.x;
    const int m0 = blockIdx.x * 128;
    const int n0 = blockIdx.y * 128;
    const int srow = tid >> 2;
    const int skq = (tid & 3) * 8;
    const int wave = tid >> 6, lane = tid & 63;
    const int wm = (wave >> 1) * 64, wn = (wave & 1) * 64;
    const int quad = lane >> 4, l15 = lane & 15;
    const bool doOut = (blockIdx.y == 0);
    const int row2 = tid >> 1, half = tid & 1;

    if (doOut) {
        float4* wf4 = (float4*)Wf;
        const float4* src4 = (const float4*)wfold;
        wf4[tid] = src4[tid];
        wf4[256 + tid] = src4[256 + tid];
    }

    f32x4 acc[4][4];
    for (int i = 0; i < 4; i++)
        for (int j = 0; j < 4; j++) acc[i][j] = f32x4{0.f, 0.f, 0.f, 0.f};
    float ox = 0.f, oy = 0.f, oz = 0.f, ow = 0.f;

    const __bf16* Abase = activated + (m0 + srow) * 256 + skq;
    const __bf16* Bbase = Wr + (n0 + srow) * 256 + skq;

    for (int ks = 0; ks < 8; ++ks) {
        int kk = ks * 32;
        g2l16(Abase + kk, &As[srow * 32 + skq]);
        g2l16(Abase + kk + 64 * 256, &As[(64 + srow) * 32 + skq]);
        g2l16(Bbase + kk, &Bs[srow * 32 + skq]);
        g2l16(Bbase + kk + 64 * 256, &Bs[(64 + srow) * 32 + skq]);
        __syncthreads();
        bf16x8 a[4], b[4];
        for (int mi = 0; mi < 4; mi++) a[mi] = *(const bf16x8*)&As[(wm + mi * 16 + l15) * 32 + quad * 8];
        for (int ni = 0; ni < 4; ni++) b[ni] = *(const bf16x8*)&Bs[(wn + ni * 16 + l15) * 32 + quad * 8];
        for (int mi = 0; mi < 4; mi++)
            for (int ni = 0; ni < 4; ni++)
                acc[mi][ni] = __builtin_amdgcn_mfma_f32_16x16x32_bf16(a[mi], b[ni], acc[mi][ni], 0, 0, 0);
        if (doOut) {
            const bf16x8* ap = (const bf16x8*)&As[row2 * 32];
            const float4* wf = (const float4*)Wf;
            for (int c8 = 0; c8 < 4; ++c8) {
                bf16x8 av = ap[c8];
                int kb = (kk + c8 * 8) * 2 + half;
                for (int e = 0; e < 8; ++e) {
                    float a = (float)av[e];
                    float4 w = wf[kb + e * 2];
                    ox += a * w.x; oy += a * w.y; oz += a * w.z; ow += a * w.w;
                }
            }
        }
        __syncthreads();
    }

    for (int ni = 0; ni < 4; ++ni) {
        int col = n0 + wn + ni * 16 + l15;
        float bcol = b_res[col];
        for (int mi = 0; mi < 4; ++mi) {
            for (int reg = 0; reg < 4; ++reg) {
                int r = m0 + wm + mi * 16 + quad * 4 + reg;
                int pr = ((r >> 12) << 13) + PAD + (r & 4095);
                int idx = pr * 256 + col;
                float f = (float)started_pad[idx] + acc[mi][ni][reg] + bcol;
                started_pad[idx] = (__bf16)f;
            }
        }
    }
    if (doOut) {
        int r = m0 + row2;
        float4* op = (float4*)&out[r * 8 + half * 4];
        float4 o;
        if (initOut) {
            float4 oc = ((const float4*)outconst)[half];
            o.x = oc.x + ox; o.y = oc.y + oy; o.z = oc.z + oz; o.w = oc.w + ow;
        } else {
            o = *op;
            o.x += ox; o.y += oy; o.z += oz; o.w += ow;
        }
        *op = o;
    }
}

// last layer: out += activated @ wfold[11]  (no res half). Grid x = m (XCD-aligned).
__global__ __launch_bounds__(256) void outacc_kernel(
    const __bf16* __restrict__ activated, const float* __restrict__ wfold,
    float* __restrict__ out) {
    __shared__ __align__(16) float Wf[2048];
    int tid = threadIdx.x;
    ((float4*)Wf)[tid] = ((const float4*)wfold)[tid];
    ((float4*)Wf)[256 + tid] = ((const float4*)wfold)[256 + tid];
    __syncthreads();
    int row2 = tid >> 1, half = tid & 1;
    int r = blockIdx.x * 128 + row2;
    const bf16x8* ap = (const bf16x8*)(activated + r * 256);
    const float4* wf = (const float4*)Wf;
    float ox = 0.f, oy = 0.f, oz = 0.f, ow = 0.f;
    for (int c8 = 0; c8 < 32; ++c8) {
        bf16x8 av = ap[c8];
        for (int e = 0; e < 8; ++e) {
            float a = (float)av[e];
            float4 w = wf[(c8 * 8 + e) * 2 + half];
            ox += a * w.x; oy += a * w.y; oz += a * w.z; ow += a * w.w;
        }
    }
    float4* op = (float4*)&out[r * 8 + half * 4];
    float4 o = *op;
    o.x += ox; o.y += oy; o.z += oz; o.w += ow;
    *op = o;
}

// ---------------- launch ----------------

extern "C" void kernel_launch(void* const* d_in, const int* in_sizes, int n_in,
                              void* d_out, int out_size, void* d_ws, size_t ws_size,
                              hipStream_t stream) {
    const float* audio      = (const float*)d_in[0];
    const float* spect      = (const float*)d_in[1];
    const float* w_start    = (const float*)d_in[2];
    const float* b_start    = (const float*)d_in[3];
    const float* w_in       = (const float*)d_in[4];
    const float* b_in       = (const float*)d_in[5];
    const float* w_cond     = (const float*)d_in[6];
    const float* b_cond     = (const float*)d_in[7];
    const float* w_res      = (const float*)d_in[8];
    const float* b_res      = (const float*)d_in[9];
    const float* w_res_last = (const float*)d_in[10];
    const float* b_res_last = (const float*)d_in[11];
    const float* w_end      = (const float*)d_in[12];
    const float* b_end      = (const float*)d_in[13];
    float* out = (float*)d_out;

    char* ws = (char*)d_ws;
    __bf16* started_pad = (__bf16*)ws; ws += 33554432;   // 65536 x 256 bf16 (padded)
    __bf16* activated   = (__bf16*)ws; ws += 16777216;   // 32768 x 256 bf16
    __bf16* spect_bf    = (__bf16*)ws; ws += 41943040;   // 32768 x 640 bf16
    __bf16* Wg          = (__bf16*)ws; ws += 17301504;   // 12 x 512 x 1408 bf16
    __bf16* Wr          = (__bf16*)ws; ws += 1441792;    // 11 x 256 x 256 bf16 (res half, [n][k])
    float*  wfold       = (float*)ws;  ws += 98304;      // 12 x 256 x 8 f32
    float*  biasg       = (float*)ws;  ws += 24576;      // 12 x 512 f32
    float*  outconst    = (float*)ws;  ws += 256;        // 8 f32

    init_started_kernel<<<dim3(65536), 256, 0, stream>>>(audio, w_start, b_start, started_pad);
    cvt_bf16_kernel<<<dim3(81920), 256, 0, stream>>>(spect, spect_bf, 20971520);
    transpose_gate<<<dim3(8, 22, 12), 256, 0, stream>>>(w_in, w_cond, Wg);
    transpose_kn<<<dim3(4, 4, 11), 256, 0, stream>>>(w_res, Wr, 256, 512, 256 * 512, 256 * 256);
    bias_gate_kernel<<<dim3(24), 256, 0, stream>>>(b_in, b_cond, biasg);
    wfold_kernel<<<dim3(97), 256, 0, stream>>>(w_res, w_res_last, w_end, b_res, b_res_last, b_end,
                                               wfold, outconst);

    for (int i = 0; i < 12; ++i) {
        gate_kernel<<<dim3(256, 4), 256, 0, stream>>>(
            started_pad, spect_bf, Wg + (size_t)i * 512 * KG, biasg + i * 512, activated, 1 << i);
        if (i < 11) {
            res_kernel<<<dim3(256, 2), 256, 0, stream>>>(
                activated, Wr + (size_t)i * 256 * 256, b_res + i * 512,
                wfold + i * 2048, outconst, started_pad, out, i == 0 ? 1 : 0);
        } else {
            outacc_kernel<<<dim3(256), 256, 0, stream>>>(activated, wfold + 11 * 2048, out);
        }
    }
}

// Round 7
// 1268.286 us; speedup vs baseline: 1.0076x; 1.0076x over previous
//
#include <hip/hip_runtime.h>
#include <cstdint>

#define PAD 2048
#define KG 1408   // 3*256 conv + 640 cond

typedef float f32x4 __attribute__((ext_vector_type(4)));
typedef __bf16 bf16x8 __attribute__((ext_vector_type(8)));
typedef __bf16 bf16x4 __attribute__((ext_vector_type(4)));

__device__ __forceinline__ void g2l16(const void* g, void* l) {
    __builtin_amdgcn_global_load_lds(
        (__attribute__((address_space(1))) void*)(uintptr_t)g,
        (__attribute__((address_space(3))) void*)(uint32_t)(uintptr_t)l,
        16, 0, 0);
}

// ---------------- setup kernels ----------------

// vectorized fp32 -> bf16 (4 elems/thread)
__global__ void cvt_bf16_kernel(const float4* __restrict__ src, bf16x4* __restrict__ dst, int n4) {
    int idx = blockIdx.x * 256 + threadIdx.x;
    if (idx < n4) {
        float4 v = src[idx];
        bf16x4 o = {(__bf16)v.x, (__bf16)v.y, (__bf16)v.z, (__bf16)v.w};
        dst[idx] = o;
    }
}

// whole padded started buffer: pad rows = 0, data rows = audio @ w_start + b_start. 4 ch/thread.
__global__ void init_started_kernel(const float* __restrict__ audio, const float* __restrict__ w_start,
                                    const float* __restrict__ b_start, __bf16* __restrict__ started_pad) {
    int pr = blockIdx.x * 4 + (threadIdx.x >> 6);
    int c0 = (threadIdx.x & 63) * 4;
    int off = pr & 8191;
    bf16x4 o = {(__bf16)0.f, (__bf16)0.f, (__bf16)0.f, (__bf16)0.f};
    if (off >= PAD && off < PAD + 4096) {
        int r = ((pr >> 13) << 12) + (off - PAD);
        float a0 = audio[r * 4 + 0], a1 = audio[r * 4 + 1], a2 = audio[r * 4 + 2], a3 = audio[r * 4 + 3];
        for (int j = 0; j < 4; ++j) {
            int c = c0 + j;
            o[j] = (__bf16)(b_start[c] + a0 * w_start[c] + a1 * w_start[256 + c]
                            + a2 * w_start[512 + c] + a3 * w_start[768 + c]);
        }
    }
    *(bf16x4*)&started_pad[(size_t)pr * 256 + c0] = o;
}

// Build Wg[i][n'][k] bf16 (n' interleaved by 16: tanh16/sig16 groups), k: 0-767 conv taps, 768-1407 cond
__global__ void transpose_gate(const float* __restrict__ w_in, const float* __restrict__ w_cond,
                               __bf16* __restrict__ Wg) {
    __shared__ float tile[64][65];
    int i = blockIdx.z;
    int k0 = blockIdx.y * 64, n0 = blockIdx.x * 64;
    int tid = threadIdx.x, c = tid & 63, rr = tid >> 6;
    for (int it = 0; it < 16; ++it) {
        int kl = it * 4 + rr;
        int k = k0 + kl;
        int np = n0 + c;
        int phys = ((np >> 4) & 1) * 256 + (np >> 5) * 16 + (np & 15);
        float v;
        if (k < 768) v = w_in[((i * 3 + (k >> 8)) * 256 + (k & 255)) * 512 + phys];
        else         v = w_cond[(i * 640 + (k - 768)) * 512 + phys];
        tile[kl][c] = v;
    }
    __syncthreads();
    for (int it = 0; it < 16; ++it) {
        int nl = it * 4 + rr;
        Wg[(size_t)(i * 512 + n0 + nl) * KG + k0 + c] = (__bf16)tile[c][nl];
    }
}

// generic K x N fp32 -> [N][K] bf16 transpose (tiles of 64x64)
__global__ void transpose_kn(const float* __restrict__ src, __bf16* __restrict__ dst,
                             int K, int N, int srcLS, int dstLS) {
    __shared__ float tile[64][65];
    int i = blockIdx.z;
    int k0 = blockIdx.y * 64, n0 = blockIdx.x * 64;
    int tid = threadIdx.x, c = tid & 63, rr = tid >> 6;
    const float* s = src + (size_t)i * srcLS;
    __bf16* dp = dst + (size_t)i * dstLS;
    for (int it = 0; it < 16; ++it) {
        int kl = it * 4 + rr;
        tile[kl][c] = s[(k0 + kl) * N + n0 + c];
    }
    __syncthreads();
    for (int it = 0; it < 16; ++it) {
        int nl = it * 4 + rr;
        dp[(size_t)(n0 + nl) * K + k0 + c] = (__bf16)tile[c][nl];
    }
}

__global__ void bias_gate_kernel(const float* __restrict__ b_in, const float* __restrict__ b_cond,
                                 float* __restrict__ bias) {
    int idx = blockIdx.x * 256 + threadIdx.x;   // 0..6143
    int i = idx >> 9, np = idx & 511;
    int phys = ((np >> 4) & 1) * 256 + (np >> 5) * 16 + (np & 15);
    bias[idx] = b_in[i * 512 + phys] + b_cond[i * 512 + phys];
}

// blocks 0..95: wfold[i][k][c] = sum_j w_res_skip[i][k][j] * w_end[j][c]  (i=11 uses w_res_last)
// block 96: outconst[c] = b_end[c] + (sum_i b_res_skip[i] + b_res_last) @ w_end
__global__ void wfold_kernel(const float* __restrict__ w_res, const float* __restrict__ w_res_last,
                             const float* __restrict__ w_end, const float* __restrict__ b_res,
                             const float* __restrict__ b_res_last, const float* __restrict__ b_end,
                             float* __restrict__ wfold, float* __restrict__ outconst) {
    if (blockIdx.x == 96) {
        __shared__ float red[256][8];
        int j = threadIdx.x;
        float bsum = b_res_last[j];
        for (int i = 0; i < 11; ++i) bsum += b_res[i * 512 + 256 + j];
        for (int c = 0; c < 8; ++c) red[j][c] = bsum * w_end[j * 8 + c];
        __syncthreads();
        if (j < 8) {
            float s = b_end[j];
            for (int t = 0; t < 256; ++t) s += red[t][j];
            outconst[j] = s;
        }
        return;
    }
    int idx = blockIdx.x * 256 + threadIdx.x;   // 0..24575
    int i = idx >> 11, rem = idx & 2047, k = rem >> 3, c = rem & 7;
    float s = 0.f;
    if (i < 11) {
        const float* wr = w_res + (size_t)(i * 256 + k) * 512 + 256;
        for (int j = 0; j < 256; ++j) s += wr[j] * w_end[j * 8 + c];
    } else {
        const float* wr = w_res_last + k * 256;
        for (int j = 0; j < 256; ++j) s += wr[j] * w_end[j * 8 + c];
    }
    wfold[idx] = s;
}

// ---------------- main GEMM kernels ----------------

// fused conv + cond + gate. LDS double-buffer, one barrier per k-step; single
// prefetch reg-set. Epilogue routes gated values through (dead) LDS staging
// buffer for coalesced bf16x8 global stores.
// Grid: x = m (fast, 256), y = n (4) so the 4 A-sharing n-blocks land on one XCD.
__global__ __launch_bounds__(256) void gate_kernel(
    const __bf16* __restrict__ started_pad, const __bf16* __restrict__ spect,
    const __bf16* __restrict__ Wg,     // layer base [512][1408]
    const float* __restrict__ bias,    // layer base [512] (interleaved order)
    __bf16* __restrict__ activated, int d) {
    __shared__ __align__(16) __bf16 S[4][128 * 32];   // As = S[0..1], Bs = S[2..3]; epilogue reuses all
    const int tid = threadIdx.x;
    const int m0 = blockIdx.x * 128;
    const int n0 = blockIdx.y * 128;
    const int padbase = ((m0 >> 12) << 13) + PAD + (m0 & 4095);
    const int srow = tid >> 2;
    const int skq = (tid & 3) * 8;
    const int wave = tid >> 6, lane = tid & 63;
    const int wm = (wave >> 1) * 64, wn = (wave & 1) * 64;
    const int quad = lane >> 4, l15 = lane & 15;

    f32x4 acc[4][4];
    for (int i = 0; i < 4; i++)
        for (int j = 0; j < 4; j++) acc[i][j] = f32x4{0.f, 0.f, 0.f, 0.f};

    const __bf16* Bbase = Wg + (n0 + srow) * KG + skq;

    bf16x8 rA0, rA1, rB0, rB1;
    auto loadTile = [&](int kk) {
        const __bf16* gA0;
        int rstride;
        if (kk < 768) {
            int tap = kk >> 8;
            int koff = kk & 255;
            gA0 = started_pad + (padbase + srow + (tap - 1) * d) * 256 + koff + skq;
            rstride = 256;
        } else {
            gA0 = spect + (m0 + srow) * 640 + (kk - 768) + skq;
            rstride = 640;
        }
        rA0 = *(const bf16x8*)gA0;
        rA1 = *(const bf16x8*)(gA0 + 64 * rstride);
        const __bf16* gB0 = Bbase + kk;
        rB0 = *(const bf16x8*)gB0;
        rB1 = *(const bf16x8*)(gB0 + 64 * KG);
    };

    // prologue: tile 0 -> buf0, tile 1 -> regs
    loadTile(0);
    *(bf16x8*)&S[0][srow * 32 + skq] = rA0;
    *(bf16x8*)&S[0][(64 + srow) * 32 + skq] = rA1;
    *(bf16x8*)&S[2][srow * 32 + skq] = rB0;
    *(bf16x8*)&S[2][(64 + srow) * 32 + skq] = rB1;
    loadTile(32);
    __syncthreads();

    for (int ks = 0; ks < 44; ++ks) {
        const int cur = ks & 1, nxt = cur ^ 1;
        bf16x8 a[4], b[4];
        for (int mi = 0; mi < 4; mi++) a[mi] = *(const bf16x8*)&S[cur][(wm + mi * 16 + l15) * 32 + quad * 8];
        for (int ni = 0; ni < 4; ni++) b[ni] = *(const bf16x8*)&S[2 + cur][(wn + ni * 16 + l15) * 32 + quad * 8];
        if (ks + 1 < 44) {
            *(bf16x8*)&S[nxt][srow * 32 + skq] = rA0;
            *(bf16x8*)&S[nxt][(64 + srow) * 32 + skq] = rA1;
            *(bf16x8*)&S[2 + nxt][srow * 32 + skq] = rB0;
            *(bf16x8*)&S[2 + nxt][(64 + srow) * 32 + skq] = rB1;
        }
        if (ks + 2 < 44) loadTile((ks + 2) * 32);
        for (int mi = 0; mi < 4; mi++)
            for (int ni = 0; ni < 4; ni++)
                acc[mi][ni] = __builtin_amdgcn_mfma_f32_16x16x32_bf16(a[mi], b[ni], acc[mi][ni], 0, 0, 0);
        __syncthreads();
    }

    // epilogue: gate, stage 128x64 activated tile in LDS (row stride 68), coalesced store.
    __bf16* tile = &S[0][0];   // 128*68 = 8704 elems <= 16384 avail
    int chloc0 = (wn >> 1) + l15;
    for (int nj = 0; nj < 2; ++nj) {
        int colT = wn + nj * 32 + l15;
        float bt = bias[n0 + colT];
        float bs = bias[n0 + colT + 16];
        int chl = chloc0 + nj * 16;
        for (int mi = 0; mi < 4; ++mi) {
            for (int reg = 0; reg < 4; ++reg) {
                int row = wm + mi * 16 + quad * 4 + reg;
                float xt = acc[mi][2 * nj][reg] + bt;
                float xs = acc[mi][2 * nj + 1][reg] + bs;
                float th = 2.f / (1.f + __expf(-2.f * xt)) - 1.f;
                float sg = 1.f / (1.f + __expf(-xs));
                tile[row * 68 + chl] = (__bf16)(th * sg);
            }
        }
    }
    __syncthreads();
    int rowb = tid >> 3, seg = tid & 7;
    int chb = n0 >> 1;
    for (int j = 0; j < 4; ++j) {
        int row = rowb + 32 * j;
        bf16x8 v = *(const bf16x8*)&tile[row * 68 + seg * 8];
        *(bf16x8*)&activated[(m0 + row) * 256 + chb + seg * 8] = v;
    }
}

// rs_res = activated @ Wr + b_res ; started_pad += rs_res (bf16 RMW)
// Grid (256,2): x = m (fast) so the reader of m-tile x sits on the XCD that produced it.
// Blocks with blockIdx.y==0 also accumulate out += activated @ wfold (init on layer 0).
__global__ __launch_bounds__(256) void res_kernel(
    const __bf16* __restrict__ activated, const __bf16* __restrict__ Wr,  // [256][256]
    const float* __restrict__ b_res,      // layer base (first 256 cols used)
    const float* __restrict__ wfold,      // layer base [256][8]
    const float* __restrict__ outconst,
    __bf16* __restrict__ started_pad, float* __restrict__ out, int initOut) {
    __shared__ __align__(16) __bf16 As[128 * 32];
    __shared__ __align__(16) __bf16 Bs[128 * 32];
    __shared__ __align__(16) float Wf[2048];   // 256 x 8
    const int tid = threadIdx.x;
    const int m0 = blockIdx.x * 128;
    const int n0 = blockIdx.y * 128;
    const int srow = tid >> 2;
    const int skq = (tid & 3) * 8;
    const int wave = tid >> 6, lane = tid & 63;
    const int wm = (wave >> 1) * 64, wn = (wave & 1) * 64;
    const int quad = lane >> 4, l15 = lane & 15;
    const bool doOut = (blockIdx.y == 0);
    const int row2 = tid >> 1, half = tid & 1;

    if (doOut) {
        float4* wf4 = (float4*)Wf;
        const float4* src4 = (const float4*)wfold;
        wf4[tid] = src4[tid];
        wf4[256 + tid] = src4[256 + tid];
    }

    f32x4 acc[4][4];
    for (int i = 0; i < 4; i++)
        for (int j = 0; j < 4; j++) acc[i][j] = f32x4{0.f, 0.f, 0.f, 0.f};
    float ox = 0.f, oy = 0.f, oz = 0.f, ow = 0.f;

    const __bf16* Abase = activated + (m0 + srow) * 256 + skq;
    const __bf16* Bbase = Wr + (n0 + srow) * 256 + skq;

    for (int ks = 0; ks < 8; ++ks) {
        int kk = ks * 32;
        g2l16(Abase + kk, &As[srow * 32 + skq]);
        g2l16(Abase + kk + 64 * 256, &As[(64 + srow) * 32 + skq]);
        g2l16(Bbase + kk, &Bs[srow * 32 + skq]);
        g2l16(Bbase + kk + 64 * 256, &Bs[(64 + srow) * 32 + skq]);
        __syncthreads();
        bf16x8 a[4], b[4];
        for (int mi = 0; mi < 4; mi++) a[mi] = *(const bf16x8*)&As[(wm + mi * 16 + l15) * 32 + quad * 8];
        for (int ni = 0; ni < 4; ni++) b[ni] = *(const bf16x8*)&Bs[(wn + ni * 16 + l15) * 32 + quad * 8];
        for (int mi = 0; mi < 4; mi++)
            for (int ni = 0; ni < 4; ni++)
                acc[mi][ni] = __builtin_amdgcn_mfma_f32_16x16x32_bf16(a[mi], b[ni], acc[mi][ni], 0, 0, 0);
        if (doOut) {
            const bf16x8* ap = (const bf16x8*)&As[row2 * 32];
            const float4* wf = (const float4*)Wf;
            for (int c8 = 0; c8 < 4; ++c8) {
                bf16x8 av = ap[c8];
                int kb = (kk + c8 * 8) * 2 + half;
                for (int e = 0; e < 8; ++e) {
                    float a = (float)av[e];
                    float4 w = wf[kb + e * 2];
                    ox += a * w.x; oy += a * w.y; oz += a * w.z; ow += a * w.w;
                }
            }
        }
        __syncthreads();
    }

    for (int ni = 0; ni < 4; ++ni) {
        int col = n0 + wn + ni * 16 + l15;
        float bcol = b_res[col];
        for (int mi = 0; mi < 4; ++mi) {
            for (int reg = 0; reg < 4; ++reg) {
                int r = m0 + wm + mi * 16 + quad * 4 + reg;
                int pr = ((r >> 12) << 13) + PAD + (r & 4095);
                int idx = pr * 256 + col;
                float f = (float)started_pad[idx] + acc[mi][ni][reg] + bcol;
                started_pad[idx] = (__bf16)f;
            }
        }
    }
    if (doOut) {
        int r = m0 + row2;
        float4* op = (float4*)&out[r * 8 + half * 4];
        float4 o;
        if (initOut) {
            float4 oc = ((const float4*)outconst)[half];
            o.x = oc.x + ox; o.y = oc.y + oy; o.z = oc.z + oz; o.w = oc.w + ow;
        } else {
            o = *op;
            o.x += ox; o.y += oy; o.z += oz; o.w += ow;
        }
        *op = o;
    }
}

// last layer: out += activated @ wfold[11]  (no res half). Grid x = m (XCD-aligned).
__global__ __launch_bounds__(256) void outacc_kernel(
    const __bf16* __restrict__ activated, const float* __restrict__ wfold,
    float* __restrict__ out) {
    __shared__ __align__(16) float Wf[2048];
    int tid = threadIdx.x;
    ((float4*)Wf)[tid] = ((const float4*)wfold)[tid];
    ((float4*)Wf)[256 + tid] = ((const float4*)wfold)[256 + tid];
    __syncthreads();
    int row2 = tid >> 1, half = tid & 1;
    int r = blockIdx.x * 128 + row2;
    const bf16x8* ap = (const bf16x8*)(activated + r * 256);
    const float4* wf = (const float4*)Wf;
    float ox = 0.f, oy = 0.f, oz = 0.f, ow = 0.f;
    for (int c8 = 0; c8 < 32; ++c8) {
        bf16x8 av = ap[c8];
        for (int e = 0; e < 8; ++e) {
            float a = (float)av[e];
            float4 w = wf[(c8 * 8 + e) * 2 + half];
            ox += a * w.x; oy += a * w.y; oz += a * w.z; ow += a * w.w;
        }
    }
    float4* op = (float4*)&out[r * 8 + half * 4];
    float4 o = *op;
    o.x += ox; o.y += oy; o.z += oz; o.w += ow;
    *op = o;
}

// ---------------- launch ----------------

extern "C" void kernel_launch(void* const* d_in, const int* in_sizes, int n_in,
                              void* d_out, int out_size, void* d_ws, size_t ws_size,
                              hipStream_t stream) {
    const float* audio      = (const float*)d_in[0];
    const float* spect      = (const float*)d_in[1];
    const float* w_start    = (const float*)d_in[2];
    const float* b_start    = (const float*)d_in[3];
    const float* w_in       = (const float*)d_in[4];
    const float* b_in       = (const float*)d_in[5];
    const float* w_cond     = (const float*)d_in[6];
    const float* b_cond     = (const float*)d_in[7];
    const float* w_res      = (const float*)d_in[8];
    const float* b_res      = (const float*)d_in[9];
    const float* w_res_last = (const float*)d_in[10];
    const float* b_res_last = (const float*)d_in[11];
    const float* w_end      = (const float*)d_in[12];
    const float* b_end      = (const float*)d_in[13];
    float* out = (float*)d_out;

    char* ws = (char*)d_ws;
    __bf16* started_pad = (__bf16*)ws; ws += 33554432;   // 65536 x 256 bf16 (padded)
    __bf16* activated   = (__bf16*)ws; ws += 16777216;   // 32768 x 256 bf16
    __bf16* spect_bf    = (__bf16*)ws; ws += 41943040;   // 32768 x 640 bf16
    __bf16* Wg          = (__bf16*)ws; ws += 17301504;   // 12 x 512 x 1408 bf16
    __bf16* Wr          = (__bf16*)ws; ws += 1441792;    // 11 x 256 x 256 bf16 (res half, [n][k])
    float*  wfold       = (float*)ws;  ws += 98304;      // 12 x 256 x 8 f32
    float*  biasg       = (float*)ws;  ws += 24576;      // 12 x 512 f32
    float*  outconst    = (float*)ws;  ws += 256;        // 8 f32

    init_started_kernel<<<dim3(16384), 256, 0, stream>>>(audio, w_start, b_start, started_pad);
    cvt_bf16_kernel<<<dim3(20480), 256, 0, stream>>>((const float4*)spect, (bf16x4*)spect_bf, 5242880);
    transpose_gate<<<dim3(8, 22, 12), 256, 0, stream>>>(w_in, w_cond, Wg);
    transpose_kn<<<dim3(4, 4, 11), 256, 0, stream>>>(w_res, Wr, 256, 512, 256 * 512, 256 * 256);
    bias_gate_kernel<<<dim3(24), 256, 0, stream>>>(b_in, b_cond, biasg);
    wfold_kernel<<<dim3(97), 256, 0, stream>>>(w_res, w_res_last, w_end, b_res, b_res_last, b_end,
                                               wfold, outconst);

    for (int i = 0; i < 12; ++i) {
        gate_kernel<<<dim3(256, 4), 256, 0, stream>>>(
            started_pad, spect_bf, Wg + (size_t)i * 512 * KG, biasg + i * 512, activated, 1 << i);
        if (i < 11) {
            res_kernel<<<dim3(256, 2), 256, 0, stream>>>(
                activated, Wr + (size_t)i * 256 * 256, b_res + i * 512,
                wfold + i * 2048, outconst, started_pad, out, i == 0 ? 1 : 0);
        } else {
            outacc_kernel<<<dim3(256), 256, 0, stream>>>(activated, wfold + 11 * 2048, out);
        }
    }
}

// Round 8
// 1097.651 us; speedup vs baseline: 1.1642x; 1.1555x over previous
//
#include <hip/hip_runtime.h>
#include <cstdint>

#define PAD 2048
#define KG 1408   // 3*256 conv + 640 cond

typedef float f32x4 __attribute__((ext_vector_type(4)));
typedef __bf16 bf16x8 __attribute__((ext_vector_type(8)));
typedef __bf16 bf16x4 __attribute__((ext_vector_type(4)));

__device__ __forceinline__ void g2l16(const void* g, void* l) {
    __builtin_amdgcn_global_load_lds(
        (__attribute__((address_space(1))) void*)(uintptr_t)g,
        (__attribute__((address_space(3))) void*)(uint32_t)(uintptr_t)l,
        16, 0, 0);
}

// ---------------- setup kernels ----------------

// vectorized fp32 -> bf16 (4 elems/thread)
__global__ void cvt_bf16_kernel(const float4* __restrict__ src, bf16x4* __restrict__ dst, int n4) {
    int idx = blockIdx.x * 256 + threadIdx.x;
    if (idx < n4) {
        float4 v = src[idx];
        bf16x4 o = {(__bf16)v.x, (__bf16)v.y, (__bf16)v.z, (__bf16)v.w};
        dst[idx] = o;
    }
}

// whole padded started buffer: pad rows = 0, data rows = audio @ w_start + b_start. 4 ch/thread.
__global__ void init_started_kernel(const float* __restrict__ audio, const float* __restrict__ w_start,
                                    const float* __restrict__ b_start, __bf16* __restrict__ started_pad) {
    int pr = blockIdx.x * 4 + (threadIdx.x >> 6);
    int c0 = (threadIdx.x & 63) * 4;
    int off = pr & 8191;
    bf16x4 o = {(__bf16)0.f, (__bf16)0.f, (__bf16)0.f, (__bf16)0.f};
    if (off >= PAD && off < PAD + 4096) {
        int r = ((pr >> 13) << 12) + (off - PAD);
        float a0 = audio[r * 4 + 0], a1 = audio[r * 4 + 1], a2 = audio[r * 4 + 2], a3 = audio[r * 4 + 3];
        for (int j = 0; j < 4; ++j) {
            int c = c0 + j;
            o[j] = (__bf16)(b_start[c] + a0 * w_start[c] + a1 * w_start[256 + c]
                            + a2 * w_start[512 + c] + a3 * w_start[768 + c]);
        }
    }
    *(bf16x4*)&started_pad[(size_t)pr * 256 + c0] = o;
}

// Build Wg[i][n'][k] bf16 (n' interleaved by 16: tanh16/sig16 groups), k: 0-767 conv taps, 768-1407 cond
__global__ void transpose_gate(const float* __restrict__ w_in, const float* __restrict__ w_cond,
                               __bf16* __restrict__ Wg) {
    __shared__ float tile[64][65];
    int i = blockIdx.z;
    int k0 = blockIdx.y * 64, n0 = blockIdx.x * 64;
    int tid = threadIdx.x, c = tid & 63, rr = tid >> 6;
    for (int it = 0; it < 16; ++it) {
        int kl = it * 4 + rr;
        int k = k0 + kl;
        int np = n0 + c;
        int phys = ((np >> 4) & 1) * 256 + (np >> 5) * 16 + (np & 15);
        float v;
        if (k < 768) v = w_in[((i * 3 + (k >> 8)) * 256 + (k & 255)) * 512 + phys];
        else         v = w_cond[(i * 640 + (k - 768)) * 512 + phys];
        tile[kl][c] = v;
    }
    __syncthreads();
    for (int it = 0; it < 16; ++it) {
        int nl = it * 4 + rr;
        Wg[(size_t)(i * 512 + n0 + nl) * KG + k0 + c] = (__bf16)tile[c][nl];
    }
}

// generic K x N fp32 -> [N][K] bf16 transpose (tiles of 64x64)
__global__ void transpose_kn(const float* __restrict__ src, __bf16* __restrict__ dst,
                             int K, int N, int srcLS, int dstLS) {
    __shared__ float tile[64][65];
    int i = blockIdx.z;
    int k0 = blockIdx.y * 64, n0 = blockIdx.x * 64;
    int tid = threadIdx.x, c = tid & 63, rr = tid >> 6;
    const float* s = src + (size_t)i * srcLS;
    __bf16* dp = dst + (size_t)i * dstLS;
    for (int it = 0; it < 16; ++it) {
        int kl = it * 4 + rr;
        tile[kl][c] = s[(k0 + kl) * N + n0 + c];
    }
    __syncthreads();
    for (int it = 0; it < 16; ++it) {
        int nl = it * 4 + rr;
        dp[(size_t)(n0 + nl) * K + k0 + c] = (__bf16)tile[c][nl];
    }
}

__global__ void bias_gate_kernel(const float* __restrict__ b_in, const float* __restrict__ b_cond,
                                 float* __restrict__ bias) {
    int idx = blockIdx.x * 256 + threadIdx.x;   // 0..6143
    int i = idx >> 9, np = idx & 511;
    int phys = ((np >> 4) & 1) * 256 + (np >> 5) * 16 + (np & 15);
    bias[idx] = b_in[i * 512 + phys] + b_cond[i * 512 + phys];
}

// blocks 0..95: wfold[i][k][c] = sum_j w_res_skip[i][k][j] * w_end[j][c]  (i=11 uses w_res_last)
// block 96: outconst[c] = b_end[c] + (sum_i b_res_skip[i] + b_res_last) @ w_end
__global__ void wfold_kernel(const float* __restrict__ w_res, const float* __restrict__ w_res_last,
                             const float* __restrict__ w_end, const float* __restrict__ b_res,
                             const float* __restrict__ b_res_last, const float* __restrict__ b_end,
                             float* __restrict__ wfold, float* __restrict__ outconst) {
    if (blockIdx.x == 96) {
        __shared__ float red[256][8];
        int j = threadIdx.x;
        float bsum = b_res_last[j];
        for (int i = 0; i < 11; ++i) bsum += b_res[i * 512 + 256 + j];
        for (int c = 0; c < 8; ++c) red[j][c] = bsum * w_end[j * 8 + c];
        __syncthreads();
        if (j < 8) {
            float s = b_end[j];
            for (int t = 0; t < 256; ++t) s += red[t][j];
            outconst[j] = s;
        }
        return;
    }
    int idx = blockIdx.x * 256 + threadIdx.x;   // 0..24575
    int i = idx >> 11, rem = idx & 2047, k = rem >> 3, c = rem & 7;
    float s = 0.f;
    if (i < 11) {
        const float* wr = w_res + (size_t)(i * 256 + k) * 512 + 256;
        for (int j = 0; j < 256; ++j) s += wr[j] * w_end[j * 8 + c];
    } else {
        const float* wr = w_res_last + k * 256;
        for (int j = 0; j < 256; ++j) s += wr[j] * w_end[j * 8 + c];
    }
    wfold[idx] = s;
}

// ---------------- main GEMM kernels ----------------

// fused conv + cond + gate. 128x256 tile (acc 4x8/wave), LDS double-buffer,
// one barrier per k-step, single prefetch reg-set.
// Grid: x = m (fast, 256), y = n (2) so A-sharing n-blocks land on one XCD.
__global__ __launch_bounds__(256, 2) void gate_kernel(
    const __bf16* __restrict__ started_pad, const __bf16* __restrict__ spect,
    const __bf16* __restrict__ Wg,     // layer base [512][1408]
    const float* __restrict__ bias,    // layer base [512] (interleaved order)
    __bf16* __restrict__ activated, int d) {
    // SMEM: As[2][128*32] at 0 / 4096, Bs[2][256*32] at 8192 / 16384; total 24576 elems = 48KB
    __shared__ __align__(16) __bf16 SMEM[24576];
    const int tid = threadIdx.x;
    const int m0 = blockIdx.x * 128;
    const int n0 = blockIdx.y * 256;
    const int padbase = ((m0 >> 12) << 13) + PAD + (m0 & 4095);
    const int srow = tid >> 2;
    const int skq = (tid & 3) * 8;
    const int wave = tid >> 6, lane = tid & 63;
    const int wm = (wave >> 1) * 64, wn = (wave & 1) * 128;
    const int quad = lane >> 4, l15 = lane & 15;

    f32x4 acc[4][8];
    for (int i = 0; i < 4; i++)
        for (int j = 0; j < 8; j++) acc[i][j] = f32x4{0.f, 0.f, 0.f, 0.f};

    const __bf16* Bbase = Wg + (n0 + srow) * KG + skq;

    bf16x8 rA[2], rB[4];
    auto loadTile = [&](int kk) {
        const __bf16* gA0;
        int rstride;
        if (kk < 768) {
            int tap = kk >> 8;
            int koff = kk & 255;
            gA0 = started_pad + (padbase + srow + (tap - 1) * d) * 256 + koff + skq;
            rstride = 256;
        } else {
            gA0 = spect + (m0 + srow) * 640 + (kk - 768) + skq;
            rstride = 640;
        }
        rA[0] = *(const bf16x8*)gA0;
        rA[1] = *(const bf16x8*)(gA0 + 64 * rstride);
        const __bf16* gB0 = Bbase + kk;
        rB[0] = *(const bf16x8*)gB0;
        rB[1] = *(const bf16x8*)(gB0 + 64 * KG);
        rB[2] = *(const bf16x8*)(gB0 + 128 * KG);
        rB[3] = *(const bf16x8*)(gB0 + 192 * KG);
    };
    auto stash = [&](int buf) {
        __bf16* Ab = SMEM + buf * 4096;
        __bf16* Bb = SMEM + 8192 + buf * 8192;
        *(bf16x8*)&Ab[srow * 32 + skq] = rA[0];
        *(bf16x8*)&Ab[(64 + srow) * 32 + skq] = rA[1];
        *(bf16x8*)&Bb[srow * 32 + skq] = rB[0];
        *(bf16x8*)&Bb[(64 + srow) * 32 + skq] = rB[1];
        *(bf16x8*)&Bb[(128 + srow) * 32 + skq] = rB[2];
        *(bf16x8*)&Bb[(192 + srow) * 32 + skq] = rB[3];
    };

    // prologue: tile 0 -> buf0, tile 1 -> regs
    loadTile(0);
    stash(0);
    loadTile(32);
    __syncthreads();

    for (int ks = 0; ks < 44; ++ks) {
        const int cur = ks & 1, nxt = cur ^ 1;
        const __bf16* Ab = SMEM + cur * 4096;
        const __bf16* Bb = SMEM + 8192 + cur * 8192;
        bf16x8 a[4], b[8];
        for (int mi = 0; mi < 4; mi++) a[mi] = *(const bf16x8*)&Ab[(wm + mi * 16 + l15) * 32 + quad * 8];
        for (int ni = 0; ni < 8; ni++) b[ni] = *(const bf16x8*)&Bb[(wn + ni * 16 + l15) * 32 + quad * 8];
        if (ks + 1 < 44) stash(nxt);
        if (ks + 2 < 44) loadTile((ks + 2) * 32);
        for (int mi = 0; mi < 4; mi++)
            for (int ni = 0; ni < 8; ni++)
                acc[mi][ni] = __builtin_amdgcn_mfma_f32_16x16x32_bf16(a[mi], b[ni], acc[mi][ni], 0, 0, 0);
        __syncthreads();
    }

    // epilogue: gate, stage 128x128 activated channels in LDS (row stride 132), coalesced store.
    __bf16* tile = SMEM;   // 128*132 = 16896 elems <= 24576
    for (int nj = 0; nj < 4; ++nj) {
        int colT = wn + nj * 32 + l15;
        float bt = bias[n0 + colT];
        float bs = bias[n0 + colT + 16];
        int chl = (wn >> 1) + nj * 16 + l15;
        for (int mi = 0; mi < 4; ++mi) {
            for (int reg = 0; reg < 4; ++reg) {
                int row = wm + mi * 16 + quad * 4 + reg;
                float xt = acc[mi][2 * nj][reg] + bt;
                float xs = acc[mi][2 * nj + 1][reg] + bs;
                float th = 2.f / (1.f + __expf(-2.f * xt)) - 1.f;
                float sg = 1.f / (1.f + __expf(-xs));
                tile[row * 132 + chl] = (__bf16)(th * sg);
            }
        }
    }
    __syncthreads();
    int chb = n0 >> 1;
    for (int pass = 0; pass < 8; ++pass) {
        int row = (tid >> 4) + 16 * pass;
        int seg = tid & 15;
        bf16x8 v = *(const bf16x8*)&tile[row * 132 + seg * 8];
        *(bf16x8*)&activated[(m0 + row) * 256 + chb + seg * 8] = v;
    }
}

// rs_res = activated @ Wr + b_res ; started_pad += rs_res (bf16 RMW)
// Grid (256,2): x = m (fast) so the reader of m-tile x sits on the XCD that produced it.
// Blocks with blockIdx.y==0 also run out += activated @ wfold via MFMA (bf16 wfold,
// 16-col B-extension in LDS; waves with wn==0 cover all 128 rows).
__global__ __launch_bounds__(256) void res_kernel(
    const __bf16* __restrict__ activated, const __bf16* __restrict__ Wr,  // [256][256]
    const float* __restrict__ b_res,      // layer base (first 256 cols used)
    const float* __restrict__ wfold,      // layer base [256][8] fp32
    const float* __restrict__ outconst,
    __bf16* __restrict__ started_pad, float* __restrict__ out, int initOut) {
    __shared__ __align__(16) __bf16 As[128 * 32];
    __shared__ __align__(16) __bf16 Bs[128 * 32];
    __shared__ __align__(16) __bf16 WfB[16 * 264];   // [col][k], cols 8..15 zero, padded stride
    const int tid = threadIdx.x;
    const int m0 = blockIdx.x * 128;
    const int n0 = blockIdx.y * 128;
    const int srow = tid >> 2;
    const int skq = (tid & 3) * 8;
    const int wave = tid >> 6, lane = tid & 63;
    const int wm = (wave >> 1) * 64, wn = (wave & 1) * 64;
    const int quad = lane >> 4, l15 = lane & 15;
    const bool doOut = (blockIdx.y == 0);
    const bool outWave = doOut && (wn == 0);

    f32x4 acc[4][4];
    for (int i = 0; i < 4; i++)
        for (int j = 0; j < 4; j++) acc[i][j] = f32x4{0.f, 0.f, 0.f, 0.f};
    f32x4 acc_o[4];
    for (int i = 0; i < 4; i++) acc_o[i] = f32x4{0.f, 0.f, 0.f, 0.f};

    const __bf16* Abase = activated + (m0 + srow) * 256 + skq;
    const __bf16* Bbase = Wr + (n0 + srow) * 256 + skq;

    if (doOut) {
        // stage wfold bf16 [16 cols][256 k] (cols 8..15 = 0)
        for (int t = 0; t < 16; ++t) {
            int e = t * 256 + tid;          // 0..4095
            int col = e >> 8, k = e & 255;
            WfB[col * 264 + k] = (col < 8) ? (__bf16)wfold[k * 8 + col] : (__bf16)0.f;
        }
    }

    for (int ks = 0; ks < 8; ++ks) {
        int kk = ks * 32;
        g2l16(Abase + kk, &As[srow * 32 + skq]);
        g2l16(Abase + kk + 64 * 256, &As[(64 + srow) * 32 + skq]);
        g2l16(Bbase + kk, &Bs[srow * 32 + skq]);
        g2l16(Bbase + kk + 64 * 256, &Bs[(64 + srow) * 32 + skq]);
        __syncthreads();
        bf16x8 a[4], b[4];
        for (int mi = 0; mi < 4; mi++) a[mi] = *(const bf16x8*)&As[(wm + mi * 16 + l15) * 32 + quad * 8];
        for (int ni = 0; ni < 4; ni++) b[ni] = *(const bf16x8*)&Bs[(wn + ni * 16 + l15) * 32 + quad * 8];
        for (int mi = 0; mi < 4; mi++)
            for (int ni = 0; ni < 4; ni++)
                acc[mi][ni] = __builtin_amdgcn_mfma_f32_16x16x32_bf16(a[mi], b[ni], acc[mi][ni], 0, 0, 0);
        if (outWave) {
            bf16x8 bx = *(const bf16x8*)&WfB[l15 * 264 + kk + quad * 8];
            for (int mi = 0; mi < 4; mi++)
                acc_o[mi] = __builtin_amdgcn_mfma_f32_16x16x32_bf16(a[mi], bx, acc_o[mi], 0, 0, 0);
        }
        __syncthreads();
    }

    for (int ni = 0; ni < 4; ++ni) {
        int col = n0 + wn + ni * 16 + l15;
        float bcol = b_res[col];
        for (int mi = 0; mi < 4; ++mi) {
            for (int reg = 0; reg < 4; ++reg) {
                int r = m0 + wm + mi * 16 + quad * 4 + reg;
                int pr = ((r >> 12) << 13) + PAD + (r & 4095);
                int idx = pr * 256 + col;
                float f = (float)started_pad[idx] + acc[mi][ni][reg] + bcol;
                started_pad[idx] = (__bf16)f;
            }
        }
    }
    if (outWave && l15 < 8) {
        for (int mi = 0; mi < 4; ++mi) {
            for (int reg = 0; reg < 4; ++reg) {
                int r = m0 + wm + mi * 16 + quad * 4 + reg;
                float base = initOut ? outconst[l15] : out[r * 8 + l15];
                out[r * 8 + l15] = base + acc_o[mi][reg];
            }
        }
    }
}

// last layer: out += activated @ wfold[11]  (no res half). Grid x = m (XCD-aligned).
__global__ __launch_bounds__(256) void outacc_kernel(
    const __bf16* __restrict__ activated, const float* __restrict__ wfold,
    float* __restrict__ out) {
    __shared__ __align__(16) float Wf[2048];
    int tid = threadIdx.x;
    ((float4*)Wf)[tid] = ((const float4*)wfold)[tid];
    ((float4*)Wf)[256 + tid] = ((const float4*)wfold)[256 + tid];
    __syncthreads();
    int row2 = tid >> 1, half = tid & 1;
    int r = blockIdx.x * 128 + row2;
    const bf16x8* ap = (const bf16x8*)(activated + r * 256);
    const float4* wf = (const float4*)Wf;
    float ox = 0.f, oy = 0.f, oz = 0.f, ow = 0.f;
    for (int c8 = 0; c8 < 32; ++c8) {
        bf16x8 av = ap[c8];
        for (int e = 0; e < 8; ++e) {
            float a = (float)av[e];
            float4 w = wf[(c8 * 8 + e) * 2 + half];
            ox += a * w.x; oy += a * w.y; oz += a * w.z; ow += a * w.w;
        }
    }
    float4* op = (float4*)&out[r * 8 + half * 4];
    float4 o = *op;
    o.x += ox; o.y += oy; o.z += oz; o.w += ow;
    *op = o;
}

// ---------------- launch ----------------

extern "C" void kernel_launch(void* const* d_in, const int* in_sizes, int n_in,
                              void* d_out, int out_size, void* d_ws, size_t ws_size,
                              hipStream_t stream) {
    const float* audio      = (const float*)d_in[0];
    const float* spect      = (const float*)d_in[1];
    const float* w_start    = (const float*)d_in[2];
    const float* b_start    = (const float*)d_in[3];
    const float* w_in       = (const float*)d_in[4];
    const float* b_in       = (const float*)d_in[5];
    const float* w_cond     = (const float*)d_in[6];
    const float* b_cond     = (const float*)d_in[7];
    const float* w_res      = (const float*)d_in[8];
    const float* b_res      = (const float*)d_in[9];
    const float* w_res_last = (const float*)d_in[10];
    const float* b_res_last = (const float*)d_in[11];
    const float* w_end      = (const float*)d_in[12];
    const float* b_end      = (const float*)d_in[13];
    float* out = (float*)d_out;

    char* ws = (char*)d_ws;
    __bf16* started_pad = (__bf16*)ws; ws += 33554432;   // 65536 x 256 bf16 (padded)
    __bf16* activated   = (__bf16*)ws; ws += 16777216;   // 32768 x 256 bf16
    __bf16* spect_bf    = (__bf16*)ws; ws += 41943040;   // 32768 x 640 bf16
    __bf16* Wg          = (__bf16*)ws; ws += 17301504;   // 12 x 512 x 1408 bf16
    __bf16* Wr          = (__bf16*)ws; ws += 1441792;    // 11 x 256 x 256 bf16 (res half, [n][k])
    float*  wfold       = (float*)ws;  ws += 98304;      // 12 x 256 x 8 f32
    float*  biasg       = (float*)ws;  ws += 24576;      // 12 x 512 f32
    float*  outconst    = (float*)ws;  ws += 256;        // 8 f32

    init_started_kernel<<<dim3(16384), 256, 0, stream>>>(audio, w_start, b_start, started_pad);
    cvt_bf16_kernel<<<dim3(20480), 256, 0, stream>>>((const float4*)spect, (bf16x4*)spect_bf, 5242880);
    transpose_gate<<<dim3(8, 22, 12), 256, 0, stream>>>(w_in, w_cond, Wg);
    transpose_kn<<<dim3(4, 4, 11), 256, 0, stream>>>(w_res, Wr, 256, 512, 256 * 512, 256 * 256);
    bias_gate_kernel<<<dim3(24), 256, 0, stream>>>(b_in, b_cond, biasg);
    wfold_kernel<<<dim3(97), 256, 0, stream>>>(w_res, w_res_last, w_end, b_res, b_res_last, b_end,
                                               wfold, outconst);

    for (int i = 0; i < 12; ++i) {
        gate_kernel<<<dim3(256, 2), 256, 0, stream>>>(
            started_pad, spect_bf, Wg + (size_t)i * 512 * KG, biasg + i * 512, activated, 1 << i);
        if (i < 11) {
            res_kernel<<<dim3(256, 2), 256, 0, stream>>>(
                activated, Wr + (size_t)i * 256 * 256, b_res + i * 512,
                wfold + i * 2048, outconst, started_pad, out, i == 0 ? 1 : 0);
        } else {
            outacc_kernel<<<dim3(256), 256, 0, stream>>>(activated, wfold + 11 * 2048, out);
        }
    }
}